// Round 3
// baseline (15969.518 us; speedup 1.0000x reference)
//
#include <hip/hip_runtime.h>
#include <hip/hip_bf16.h>

// SLSTM recurrence + Linear.  B=1024, T=2048, IN=16, H=128, OUT=1.
// 128 WGs x 256 thr (4 waves = 1 wave/SIMD). WG = (batch group bg of 16 rows,
// column half ch). Each WG computes gates for its 64 h-cols (4 M-tiles/wave =
// i,f,g,o for 16 cols) with K=160 = [h(128) | x(16) | pad]; per-step h-half
// exchange with partner WG (blockIdx^64, same XCD slot under round-robin) via
// d_ws agent-scope atomics + monotone flag handshake (double-buffered; signed
// flag compare makes 0xAA poison read as "not ready").
// Weights/bias pre-scaled by -log2e (i,f,o) / +2log2e (g) so exp2 args come
// straight from MFMA; shared-rcp algebra: 8 transcendentals/element.
// x pre-converted to bf16 B-fragment form in LDS, 32-step chunks.

#define T_LEN 2048
#define IN_DIM 16
#define CHUNK 32

typedef __attribute__((ext_vector_type(4))) float f32x4;
typedef __attribute__((ext_vector_type(8))) short s16x8;
typedef __attribute__((ext_vector_type(4))) short s16x4;
typedef unsigned long long u64;

__device__ __forceinline__ short f2bf(float f) {
    union { float f; unsigned u; } v; v.f = f;
    unsigned r = v.u + 0x7fffu + ((v.u >> 16) & 1u);   // RNE
    return (short)(r >> 16);
}

__global__ __launch_bounds__(256, 1)
void slstm_split(const float* __restrict__ x,
                 const float* __restrict__ W_ih,
                 const float* __restrict__ W_hh,
                 const float* __restrict__ b_ih,
                 const float* __restrict__ b_hh,
                 const float* __restrict__ fc_w,
                 const float* __restrict__ fc_b,
                 float* __restrict__ out,
                 char* __restrict__ ws)
{
    __shared__ __align__(16) unsigned short hlds[2][2][512];        // own 2 frags, dbuf (4 KB)
    __shared__ __align__(16) unsigned short xlds[CHUNK][2][16][8];  // x frags, 16 KB
    __shared__ __align__(16) unsigned short xzero[8];
    __shared__ float red[16];

    const int tid  = threadIdx.x;
    const int lane = tid & 63;
    const int wv   = tid >> 6;          // wave 0..3
    const int c16  = lane & 15;         // batch row / D col
    const int quad = lane >> 4;
    const int wgid = blockIdx.x;
    const int bg   = wgid & 63;         // batch group
    const int ch   = wgid >> 6;         // column half
    const int pid  = wgid ^ 64;         // partner WG

    int*  flags = (int*)ws;             // flag i at int-index i*64 (256 B apart)
    char* hb    = ws + 32768;
    u64*       myb0 = (u64*)(hb + (size_t)wgid * 4096);
    u64*       myb1 = (u64*)(hb + (size_t)wgid * 4096 + 2048);
    const u64* pb0  = (const u64*)(hb + (size_t)pid * 4096);
    const u64* pb1  = (const u64*)(hb + (size_t)pid * 4096 + 2048);

    // ---- weights, pre-scaled, stored in MFMA-order: idx 0,1=own h-frags, 2=x, 3,4=partner
    const float kL2E = 1.44269504f;
    s16x8 wfrag[4][5];
    float biasv[4][4];
    #pragma unroll
    for (int g = 0; g < 4; ++g) {
        const float scale = (g == 2) ? (2.0f * kL2E) : (-kL2E);
        const int n = g * 128 + ch * 64 + wv * 16 + c16;
        #pragma unroll
        for (int idx = 0; idx < 5; ++idx) {
            const int kf = (idx < 2) ? (2 * ch + idx)
                         : (idx == 2) ? 4 : (2 * (1 - ch) + idx - 3);
            s16x8 fr;
            #pragma unroll
            for (int j = 0; j < 8; ++j) {
                const int k = kf * 32 + quad * 8 + j;
                float v;
                if (kf < 4) v = W_hh[n * 128 + k];
                else {
                    const int kk = k - 128;
                    v = (kk < IN_DIM) ? W_ih[n * IN_DIM + kk] : 0.0f;
                }
                fr[j] = f2bf(v * scale);
            }
            wfrag[g][idx] = fr;
        }
        #pragma unroll
        for (int r = 0; r < 4; ++r) {
            const int m = g * 128 + ch * 64 + wv * 16 + quad * 4 + r;
            biasv[g][r] = (b_ih[m] + b_hh[m]) * scale;
        }
    }

    // ---- init LDS ----
    for (int i = tid; i < 1024; i += 256) ((unsigned short*)hlds[0])[i] = 0;  // h0 = 0 (buf 0)
    if (tid < 8) xzero[tid] = 0;

    // writer position of this lane's 4 h values (cols ch*64 + wv*16 + quad*4 + r)
    const int s_own = wv >> 1;                        // local frag slot
    const int kq_w  = (wv & 1) * 2 + (quad >> 1);
    const int widx  = (kq_w * 16 + c16) * 8 + (quad & 1) * 4;   // shorts within slot
    const int wq    = s_own * 128 + (widx >> 2);                // u64 index within 2 KB buf

    float c_st[4] = {0.f, 0.f, 0.f, 0.f};
    float hreg[4] = {0.f, 0.f, 0.f, 0.f};
    const bool xq = (quad < 2);
    const float* xb_base = x + (size_t)(bg * 16) * (T_LEN * IN_DIM);

    __syncthreads();

    for (int t = 0; t < T_LEN; ++t) {
        // ---- refill x chunk (every 32 steps) ----
        if ((t & (CHUNK - 1)) == 0) {
            const float* xb = xb_base + (size_t)t * IN_DIM;
            #pragma unroll
            for (int k8 = 0; k8 < 8; ++k8) {
                const int flat4 = k8 * 1024 + tid * 4;
                const int b_loc = flat4 >> 9;
                const int rem   = flat4 & 511;
                f32x4 v4 = *(const f32x4*)(xb + (size_t)b_loc * (T_LEN * IN_DIM) + rem);
                s16x4 c4;
                #pragma unroll
                for (int j = 0; j < 4; ++j) c4[j] = f2bf(v4[j]);
                const int tt = rem >> 4, i0 = rem & 15;
                *(s16x4*)&xlds[tt][i0 >> 3][b_loc][i0 & 7] = c4;
            }
            __syncthreads();
        }

        const int buf = t & 1;

        // ---- partner h-frags (global, agent-coherent) ----
        s16x8 pz0, pz1;
        if (t > 0) {
            while ((int)__hip_atomic_load(&flags[pid * 64], __ATOMIC_ACQUIRE,
                                          __HIP_MEMORY_SCOPE_AGENT) < t) {}
            const u64* p = buf ? pb1 : pb0;
            u64 d0 = __hip_atomic_load(p + lane * 2,       __ATOMIC_RELAXED, __HIP_MEMORY_SCOPE_AGENT);
            u64 d1 = __hip_atomic_load(p + lane * 2 + 1,   __ATOMIC_RELAXED, __HIP_MEMORY_SCOPE_AGENT);
            u64 d2 = __hip_atomic_load(p + 128 + lane * 2, __ATOMIC_RELAXED, __HIP_MEMORY_SCOPE_AGENT);
            u64 d3 = __hip_atomic_load(p + 129 + lane * 2, __ATOMIC_RELAXED, __HIP_MEMORY_SCOPE_AGENT);
            union { u64 q[2]; s16x8 v; } u0, u1;
            u0.q[0] = d0; u0.q[1] = d1; u1.q[0] = d2; u1.q[1] = d3;
            pz0 = u0.v; pz1 = u1.v;
        } else {
            pz0 = s16x8{0,0,0,0,0,0,0,0};
            pz1 = s16x8{0,0,0,0,0,0,0,0};
        }

        // ---- own + x frags ----
        s16x8 zf0 = *(const s16x8*)&hlds[buf][0][lane * 8];
        s16x8 zf1 = *(const s16x8*)&hlds[buf][1][lane * 8];
        const unsigned short* xsrc = xq ? &xlds[t & (CHUNK - 1)][quad][c16][0] : xzero;
        s16x8 zx = *(const s16x8*)xsrc;

        s16x8 zfo[5];
        zfo[0] = zf0; zfo[1] = zf1; zfo[2] = zx; zfo[3] = pz0; zfo[4] = pz1;

        // ---- 20 MFMAs (own frags first; partner loads covered by own+x work) ----
        f32x4 acc[4];
        #pragma unroll
        for (int g = 0; g < 4; ++g) {
            f32x4 a; a[0] = biasv[g][0]; a[1] = biasv[g][1]; a[2] = biasv[g][2]; a[3] = biasv[g][3];
            acc[g] = a;
        }
        #pragma unroll
        for (int idx = 0; idx < 5; ++idx)
            #pragma unroll
            for (int g = 0; g < 4; ++g)
                acc[g] = __builtin_amdgcn_mfma_f32_16x16x32_bf16(wfrag[g][idx], zfo[idx], acc[g], 0, 0, 0);

        // ---- elementwise (pre-scaled): e = exp2(acc) directly; shared-rcp algebra ----
        s16x4 hv;
        #pragma unroll
        for (int r = 0; r < 4; ++r) {
            const float ei = __builtin_amdgcn_exp2f(fminf(acc[0][r], 60.f));  // e^{-i}
            const float ef = __builtin_amdgcn_exp2f(fminf(acc[1][r], 60.f));  // e^{-f}
            const float eg = __builtin_amdgcn_exp2f(fminf(acc[2][r], 60.f));  // e^{2g}
            const float eo = __builtin_amdgcn_exp2f(fminf(acc[3][r], 60.f));  // e^{-o}
            const float tg = (eg - 1.0f) * __builtin_amdgcn_rcpf(eg + 1.0f);
            const float A  = 1.0f + ei, Bf = 1.0f + ef;
            const float num = fmaf(tg, Bf, c_st[r] * A);
            const float cn  = num * __builtin_amdgcn_rcpf(A * Bf);
            c_st[r] = cn;
            const float ec = __builtin_amdgcn_exp2f(fminf(cn * (2.0f * kL2E), 60.f));
            const float hn = (ec - 1.0f) * __builtin_amdgcn_rcpf((ec + 1.0f) * (1.0f + eo));
            hreg[r] = hn;
            hv[r] = f2bf(hn);
        }

        // ---- publish h: own LDS copy + partner global copy ----
        *(s16x4*)&hlds[buf ^ 1][s_own][widx] = hv;
        union { s16x4 v; u64 q; } uw; uw.v = hv;
        __hip_atomic_store((buf ? myb0 : myb1) + wq, uw.q, __ATOMIC_RELAXED, __HIP_MEMORY_SCOPE_AGENT);

        __syncthreads();                 // drains vmem (stores visible) + LDS sync
        if (tid == 0)
            __hip_atomic_store(&flags[wgid * 64], t + 1, __ATOMIC_RELEASE, __HIP_MEMORY_SCOPE_AGENT);
    }

    // ---- epilogue: out[b] = sum_cols h * fc_w + fc_b, combined across the pair ----
    float v = 0.0f;
    #pragma unroll
    for (int r = 0; r < 4; ++r)
        v = fmaf(hreg[r], fc_w[ch * 64 + wv * 16 + quad * 4 + r], v);
    v += __shfl_xor(v, 16);
    v += __shfl_xor(v, 32);                      // sum over quad
    if (tid < 16) red[tid] = 0.0f;
    __syncthreads();
    if (lane < 16) atomicAdd(&red[c16], v);      // combine 4 waves
    __syncthreads();

    if (ch == 1) {
        if (tid < 16)
            __hip_atomic_store((float*)myb0 + tid, red[tid], __ATOMIC_RELAXED, __HIP_MEMORY_SCOPE_AGENT);
        __syncthreads();
        if (tid == 0)
            __hip_atomic_store(&flags[wgid * 64], T_LEN + 1, __ATOMIC_RELEASE, __HIP_MEMORY_SCOPE_AGENT);
    } else {
        if (tid == 0)
            while ((int)__hip_atomic_load(&flags[pid * 64], __ATOMIC_ACQUIRE,
                                          __HIP_MEMORY_SCOPE_AGENT) < T_LEN + 1) {}
        __syncthreads();
        if (tid < 16) {
            float pv = __hip_atomic_load((const float*)pb0 + tid, __ATOMIC_RELAXED, __HIP_MEMORY_SCOPE_AGENT);
            out[bg * 16 + tid] = red[tid] + pv + fc_b[0];
        }
    }
}

extern "C" void kernel_launch(void* const* d_in, const int* in_sizes, int n_in,
                              void* d_out, int out_size, void* d_ws, size_t ws_size,
                              hipStream_t stream) {
    const float* x    = (const float*)d_in[0];
    const float* W_ih = (const float*)d_in[1];
    const float* W_hh = (const float*)d_in[2];
    const float* b_ih = (const float*)d_in[3];
    const float* b_hh = (const float*)d_in[4];
    const float* fc_w = (const float*)d_in[5];
    const float* fc_b = (const float*)d_in[6];
    float* out = (float*)d_out;

    slstm_split<<<128, 256, 0, stream>>>(x, W_ih, W_hh, b_ih, b_hh, fc_w, fc_b, out, (char*)d_ws);
}

// Round 4
// 1978.291 us; speedup vs baseline: 8.0724x; 8.0724x over previous
//
#include <hip/hip_runtime.h>
#include <hip/hip_bf16.h>

// SLSTM recurrence + Linear.  B=1024, T=2048, IN=16, H=128, OUT=1.
// 64 persistent WGs x 512 thr (R2 structure: 1 WG per 16 batch rows, all T steps).
// gates^T (512x16) = W'(512x160) @ [h|x]^T via mfma_f32_16x16x32_bf16,
// A=pre-scaled weights in regs, B=[h|x] frags; h in LDS in fragment order
// (conflict-free b128 reads / b64 writes), double-buffered, 1 barrier/step.
// R4 changes vs R2: (a) weights/bias pre-scaled by -log2e (i,f,o) / -2log2e (g)
// so exp2 args come straight from MFMA; (b) single-rcp LSTM algebra: 7 trans/elem
// (5 exp2 + 2 rcp) vs 10; (c) bias rides the MFMA C operand (no acc-init movs);
// (d) x pre-converted to bf16 fragment form in LDS in 32-step chunks.
// R3 lesson: cross-WG per-step exchange = HBM round trips (no cross-XCD coherent
// cache) -> 64 CUs is structural; minimize per-CU VALU instead.

#define T_LEN 2048
#define IN_DIM 16
#define CHUNK 32

typedef __attribute__((ext_vector_type(4))) float f32x4;
typedef __attribute__((ext_vector_type(8))) short s16x8;
typedef __attribute__((ext_vector_type(4))) short s16x4;

__device__ __forceinline__ short f2bf(float f) {
    union { float f; unsigned u; } v; v.f = f;
    unsigned r = v.u + 0x7fffu + ((v.u >> 16) & 1u);   // RNE
    return (short)(r >> 16);
}

__global__ __launch_bounds__(512, 2)
void slstm_persistent(const float* __restrict__ x,
                      const float* __restrict__ W_ih,
                      const float* __restrict__ W_hh,
                      const float* __restrict__ b_ih,
                      const float* __restrict__ b_hh,
                      const float* __restrict__ fc_w,
                      const float* __restrict__ fc_b,
                      float* __restrict__ out)
{
    // fragment-ordered h, double-buffered: element(k,n) at (k>>3)*128 + n*8 + (k&7)
    __shared__ __align__(16) unsigned short h_frag[2][4096];        // 16 KB
    __shared__ __align__(16) unsigned short xlds[CHUNK][2][16][8];  // 16 KB
    __shared__ __align__(16) unsigned short xzero[8];
    __shared__ float red[16];

    const int tid  = threadIdx.x;
    const int lane = tid & 63;
    const int wv   = tid >> 6;          // wave 0..7
    const int c16  = lane & 15;         // batch row / D col
    const int quad = lane >> 4;         // 0..3
    const int b0   = blockIdx.x * 16;

    const float kNL2E = -1.44269504f;   // -log2(e)

    // ---- A-operand weights, PRE-SCALED: wfrag[g][kf] = scale_g * W'[gate][k] ----
    s16x8 wfrag[4][5];
    f32x4 biasC[4];                     // pre-scaled bias, rides the MFMA C operand
    #pragma unroll
    for (int g = 0; g < 4; ++g) {
        const float scale = (g == 2) ? (2.0f * kNL2E) : kNL2E;
        const int n = g * 128 + wv * 16 + c16;
        #pragma unroll
        for (int kf = 0; kf < 5; ++kf) {
            s16x8 fr;
            #pragma unroll
            for (int j = 0; j < 8; ++j) {
                const int k = kf * 32 + quad * 8 + j;
                float v;
                if (kf < 4) v = W_hh[n * 128 + k];
                else {
                    const int kk = k - 128;
                    v = (kk < IN_DIM) ? W_ih[n * IN_DIM + kk] : 0.0f;
                }
                fr[j] = f2bf(v * scale);
            }
            wfrag[g][kf] = fr;
        }
        #pragma unroll
        for (int r = 0; r < 4; ++r) {
            const int m = g * 128 + wv * 16 + quad * 4 + r;
            biasC[g][r] = (b_ih[m] + b_hh[m]) * scale;
        }
    }

    // ---- init: h0 = 0 (buffer 0 only; buffer 1 is written at t=0) ----
    for (int i = tid; i < 4096; i += 512) h_frag[0][i] = 0;
    if (tid < 8) xzero[tid] = 0;

    // writer position of this lane's 4 h values (cols wv*16+quad*4+r, batch c16)
    const int kfw   = wv >> 1;
    const int quadw = (wv & 1) * 2 + (quad >> 1);
    const int widx  = ((kfw * 4 + quadw) * 16 + c16) * 8 + (quad & 1) * 4;

    float c_st[4] = {0.f, 0.f, 0.f, 0.f};
    float hreg[4] = {0.f, 0.f, 0.f, 0.f};
    const bool xq = (quad < 2);

    for (int t = 0; t < T_LEN; ++t) {
        // ---- refill x chunk: 16 rows x 32 steps x 16 feats, bf16 frag order ----
        if ((t & (CHUNK - 1)) == 0) {
            const float* xb = x + (size_t)b0 * (T_LEN * IN_DIM) + t * IN_DIM;
            #pragma unroll
            for (int k4 = 0; k4 < 4; ++k4) {
                const int flat4 = k4 * 2048 + tid * 4;
                const int b_loc = flat4 >> 9;         // 512 floats per row-chunk
                const int rem   = flat4 & 511;
                f32x4 v4 = *(const f32x4*)(xb + (size_t)b_loc * (T_LEN * IN_DIM) + rem);
                s16x4 c4;
                #pragma unroll
                for (int j = 0; j < 4; ++j) c4[j] = f2bf(v4[j]);
                *(s16x4*)&xlds[rem >> 4][(rem & 15) >> 3][b_loc][rem & 7] = c4;
            }
            __syncthreads();
        }

        const int buf = t & 1;

        // ---- B-frags: h (conflict-free b128) + x from LDS ----
        s16x8 zf[5];
        #pragma unroll
        for (int kf = 0; kf < 4; ++kf)
            zf[kf] = *(const s16x8*)&h_frag[buf][(kf * 4 + quad) * 128 + c16 * 8];
        {
            const unsigned short* xsrc =
                xq ? &xlds[t & (CHUNK - 1)][quad][c16][0] : xzero;
            zf[4] = *(const s16x8*)xsrc;
        }

        // ---- 20 MFMAs, bias as initial C (no acc-init movs) ----
        f32x4 acc[4];
        #pragma unroll
        for (int g = 0; g < 4; ++g)
            acc[g] = __builtin_amdgcn_mfma_f32_16x16x32_bf16(wfrag[g][0], zf[0], biasC[g], 0, 0, 0);
        #pragma unroll
        for (int kf = 1; kf < 5; ++kf)
            #pragma unroll
            for (int g = 0; g < 4; ++g)
                acc[g] = __builtin_amdgcn_mfma_f32_16x16x32_bf16(wfrag[g][kf], zf[kf], acc[g], 0, 0, 0);

        // ---- elementwise: 5 exp2 + 2 rcp per element (pre-scaled args) ----
        // ei=e^{-i}, ef=e^{-f}, eg=e^{-2g}, eo=e^{-o}, ec=e^{-2c'}
        // c' = [c(1+ei)(1+eg) + (1-eg)(1+ef)] / [(1+ef)(1+ei)(1+eg)]
        // h  = (1-ec) / [(1+eo)(1+ec)]
        s16x4 hv;
        #pragma unroll
        for (int r = 0; r < 4; ++r) {
            const float ei = __builtin_amdgcn_exp2f(fminf(acc[0][r], 40.f));
            const float ef = __builtin_amdgcn_exp2f(fminf(acc[1][r], 40.f));
            const float eg = __builtin_amdgcn_exp2f(fminf(acc[2][r], 40.f));
            const float eo = __builtin_amdgcn_exp2f(fminf(acc[3][r], 40.f));
            const float af = 1.0f + ef;
            const float t1 = (1.0f + ei) * (1.0f + eg);
            const float num = fmaf(c_st[r], t1, (1.0f - eg) * af);
            const float cn  = num * __builtin_amdgcn_rcpf(af * t1);
            c_st[r] = cn;
            const float ec = __builtin_amdgcn_exp2f(fminf(cn * (2.0f * kNL2E), 40.f));
            const float hn = (1.0f - ec) *
                             __builtin_amdgcn_rcpf((1.0f + eo) * (1.0f + ec));
            hreg[r] = hn;
            hv[r] = f2bf(hn);
        }

        *(s16x4*)&h_frag[buf ^ 1][widx] = hv;   // one conflict-free ds_write_b64
        __syncthreads();
    }

    // ---- epilogue: out[b] = sum_cols h * fc_w + fc_b ----
    float v = 0.0f;
    #pragma unroll
    for (int r = 0; r < 4; ++r)
        v = fmaf(hreg[r], fc_w[wv * 16 + quad * 4 + r], v);
    v += __shfl_xor(v, 16);
    v += __shfl_xor(v, 32);                     // reduce over quad (same c16)
    if (tid < 16) red[tid] = 0.0f;
    __syncthreads();
    if (lane < 16) atomicAdd(&red[c16], v);     // combine 8 waves
    __syncthreads();
    if (tid < 16) out[b0 + tid] = red[tid] + fc_b[0];
}

extern "C" void kernel_launch(void* const* d_in, const int* in_sizes, int n_in,
                              void* d_out, int out_size, void* d_ws, size_t ws_size,
                              hipStream_t stream) {
    const float* x    = (const float*)d_in[0];
    const float* W_ih = (const float*)d_in[1];
    const float* W_hh = (const float*)d_in[2];
    const float* b_ih = (const float*)d_in[3];
    const float* b_hh = (const float*)d_in[4];
    const float* fc_w = (const float*)d_in[5];
    const float* fc_b = (const float*)d_in[6];
    float* out = (float*)d_out;

    slstm_persistent<<<64, 512, 0, stream>>>(x, W_ih, W_hh, b_ih, b_hh, fc_w, fc_b, out);
}

// Round 6
// 1821.200 us; speedup vs baseline: 8.7687x; 1.0863x over previous
//
#include <hip/hip_runtime.h>
#include <hip/hip_bf16.h>

// SLSTM recurrence + Linear.  B=1024, T=2048, IN=16, H=128, OUT=1.
// 64 persistent WGs x 512 thr; WG owns 16 batch rows for all T steps.
// gates^T (512x16) = W'(512x160) @ [h|x]^T via mfma_f32_16x16x32_bf16,
// A=pre-scaled weights in regs (exp2-ready args), bias rides MFMA C operand,
// h in LDS in fragment order (conflict-free b128 reads / b32 writes), dbuf.
// R6 = R5 with the unsigned2 typo fixed (u32x2 ext vector for the 8B LDS store).
// R5 changes vs R4: (a) elementwise algebra on f32x2 pairs -> VOP3P v_pk_*_f32;
// (b) v_cvt_pk_bf16_f32 for h stores (builtin-guarded, manual RNE fallback);
// (c) T-loop unrolled x2 (constant bufs); (d) x chunk prefetched 32 steps
// ahead into regs (HBM latency hidden); (e) x-frag addr = base + slot*stride.
// Cycle model: step 2216 = 1390 VALU (trans ~900) + 825 exposed; target ~1120+~700.

#define T_LEN 2048
#define IN_DIM 16
#define CHUNK 32

typedef __attribute__((ext_vector_type(4))) float f32x4;
typedef __attribute__((ext_vector_type(2))) float f32x2;
typedef __attribute__((ext_vector_type(8))) short s16x8;
typedef __attribute__((ext_vector_type(4))) short s16x4;
typedef __attribute__((ext_vector_type(2))) unsigned u32x2;

__device__ __forceinline__ short f2bf(float f) {
    union { float f; unsigned u; } v; v.f = f;
    unsigned r = v.u + 0x7fffu + ((v.u >> 16) & 1u);   // RNE
    return (short)(r >> 16);
}

// pack two f32 -> two bf16 (RNE) in one dword
__device__ __forceinline__ unsigned pk_bf16(float a, float b) {
#if __has_builtin(__builtin_amdgcn_cvt_pk_bf16_f32)
    typedef __attribute__((ext_vector_type(2))) __bf16 bf16x2;
    bf16x2 r = __builtin_amdgcn_cvt_pk_bf16_f32(a, b);
    union { bf16x2 v; unsigned u; } c; c.v = r;
    return c.u;
#else
    return (unsigned)(unsigned short)f2bf(a) | ((unsigned)(unsigned short)f2bf(b) << 16);
#endif
}

__global__ __launch_bounds__(512, 2)
void slstm_persistent(const float* __restrict__ x,
                      const float* __restrict__ W_ih,
                      const float* __restrict__ W_hh,
                      const float* __restrict__ b_ih,
                      const float* __restrict__ b_hh,
                      const float* __restrict__ fc_w,
                      const float* __restrict__ fc_b,
                      float* __restrict__ out)
{
    // fragment-ordered h, double-buffered
    __shared__ __align__(16) unsigned short h_frag[2][4096];        // 16 KB
    __shared__ __align__(16) unsigned short xlds[CHUNK][2][16][8];  // 16 KB
    __shared__ __align__(16) unsigned short xzero[8];
    __shared__ float red[16];

    const int tid  = threadIdx.x;
    const int lane = tid & 63;
    const int wv   = tid >> 6;          // wave 0..7
    const int c16  = lane & 15;         // batch row / D col
    const int quad = lane >> 4;         // 0..3
    const int b0   = blockIdx.x * 16;

    const float kNL2E = -1.44269504f;   // -log2(e)

    // ---- A-operand weights, pre-scaled so exp2 args come straight from MFMA ----
    s16x8 wfrag[4][5];
    f32x4 biasC[4];
    #pragma unroll
    for (int g = 0; g < 4; ++g) {
        const float scale = (g == 2) ? (2.0f * kNL2E) : kNL2E;
        const int n = g * 128 + wv * 16 + c16;
        #pragma unroll
        for (int kf = 0; kf < 5; ++kf) {
            s16x8 fr;
            #pragma unroll
            for (int j = 0; j < 8; ++j) {
                const int k = kf * 32 + quad * 8 + j;
                float v;
                if (kf < 4) v = W_hh[n * 128 + k];
                else {
                    const int kk = k - 128;
                    v = (kk < IN_DIM) ? W_ih[n * IN_DIM + kk] : 0.0f;
                }
                fr[j] = f2bf(v * scale);
            }
            wfrag[g][kf] = fr;
        }
        #pragma unroll
        for (int r = 0; r < 4; ++r) {
            const int m = g * 128 + wv * 16 + quad * 4 + r;
            biasC[g][r] = (b_ih[m] + b_hh[m]) * scale;
        }
    }

    for (int i = tid; i < 4096; i += 512) h_frag[0][i] = 0;   // h0 = 0
    if (tid < 8) xzero[tid] = 0;

    // writer position of this lane's 4 h values (cols wv*16+quad*4+r, batch c16)
    const int kfw   = wv >> 1;
    const int quadw = (wv & 1) * 2 + (quad >> 1);
    const int widx  = ((kfw * 4 + quadw) * 16 + c16) * 8 + (quad & 1) * 4;
    unsigned* const wp0 = (unsigned*)&h_frag[0][widx];
    unsigned* const wp1 = (unsigned*)&h_frag[1][widx];

    // x-frag read: base + slot*stride (stride 0 for quads 2,3 -> xzero)
    const bool xq = (quad < 2);
    const unsigned short* const xbase = xq ? &xlds[0][quad][c16][0] : xzero;
    const int xstride = xq ? (2 * 16 * 8) : 0;   // shorts per slot

    f32x2 c01 = {0.f, 0.f}, c23 = {0.f, 0.f};
    float hreg[4] = {0.f, 0.f, 0.f, 0.f};

    // ---- prime x chunk 0 into regs ----
    f32x4 xreg[4];
    {
        const float* xb = x + (size_t)b0 * (T_LEN * IN_DIM);
        #pragma unroll
        for (int k4 = 0; k4 < 4; ++k4) {
            const int flat4 = k4 * 2048 + tid * 4;
            xreg[k4] = *(const f32x4*)(xb + (size_t)(flat4 >> 9) * (T_LEN * IN_DIM) + (flat4 & 511));
        }
    }

    const f32x2 kone  = {1.f, 1.f};
    const f32x2 kn2l  = {2.0f * kNL2E, 2.0f * kNL2E};

    // one timestep: read h from buf RB, write to buf WB, x slot = slot
    auto step_fn = [&](const int RB, const int WB, const int slot) {
        // B-frags: h (conflict-free b128) + x
        s16x8 zf[5];
        #pragma unroll
        for (int kf = 0; kf < 4; ++kf)
            zf[kf] = *(const s16x8*)&h_frag[RB][(kf * 4 + quad) * 128 + c16 * 8];
        zf[4] = *(const s16x8*)(xbase + slot * xstride);

        // 20 MFMAs, bias as initial C
        f32x4 acc[4];
        #pragma unroll
        for (int g = 0; g < 4; ++g)
            acc[g] = __builtin_amdgcn_mfma_f32_16x16x32_bf16(wfrag[g][0], zf[0], biasC[g], 0, 0, 0);
        #pragma unroll
        for (int kf = 1; kf < 5; ++kf)
            #pragma unroll
            for (int g = 0; g < 4; ++g)
                acc[g] = __builtin_amdgcn_mfma_f32_16x16x32_bf16(wfrag[g][kf], zf[kf], acc[g], 0, 0, 0);

        // elementwise on f32x2 pairs (VOP3P-friendly):
        // ei=e^{-i}, ef=e^{-f}, eg=e^{-2g}, eo=e^{-o}, ec=e^{-2c'}
        // c' = [c(1+ei)(1+eg) + (1-eg)(1+ef)] / [(1+ef)(1+ei)(1+eg)]
        // h  = (1-ec) / [(1+eo)(1+ec)]
        unsigned* wp = (WB == 0) ? wp0 : wp1;
        #pragma unroll
        for (int p = 0; p < 2; ++p) {
            f32x2 ai  = {fminf(acc[0][2*p], 40.f), fminf(acc[0][2*p+1], 40.f)};
            f32x2 af_ = {fminf(acc[1][2*p], 40.f), fminf(acc[1][2*p+1], 40.f)};
            f32x2 ag  = {fminf(acc[2][2*p], 40.f), fminf(acc[2][2*p+1], 40.f)};
            f32x2 ao  = {fminf(acc[3][2*p], 40.f), fminf(acc[3][2*p+1], 40.f)};
            f32x2 ei = {__builtin_amdgcn_exp2f(ai[0]),  __builtin_amdgcn_exp2f(ai[1])};
            f32x2 ef = {__builtin_amdgcn_exp2f(af_[0]), __builtin_amdgcn_exp2f(af_[1])};
            f32x2 eg = {__builtin_amdgcn_exp2f(ag[0]),  __builtin_amdgcn_exp2f(ag[1])};
            f32x2 eo = {__builtin_amdgcn_exp2f(ao[0]),  __builtin_amdgcn_exp2f(ao[1])};

            f32x2 afv = kone + ef;
            f32x2 t1  = (kone + ei) * (kone + eg);
            f32x2 cpr = (p == 0) ? c01 : c23;
            f32x2 num = cpr * t1 + (kone - eg) * afv;
            f32x2 den = afv * t1;
            f32x2 rd  = {__builtin_amdgcn_rcpf(den[0]), __builtin_amdgcn_rcpf(den[1])};
            f32x2 cn  = num * rd;
            if (p == 0) c01 = cn; else c23 = cn;

            f32x2 eca = cn * kn2l;
            eca = {fminf(eca[0], 40.f), fminf(eca[1], 40.f)};
            f32x2 ec  = {__builtin_amdgcn_exp2f(eca[0]), __builtin_amdgcn_exp2f(eca[1])};
            f32x2 dh  = (kone + eo) * (kone + ec);
            f32x2 rh  = {__builtin_amdgcn_rcpf(dh[0]), __builtin_amdgcn_rcpf(dh[1])};
            f32x2 hn  = (kone - ec) * rh;
            hreg[2*p]     = hn[0];
            hreg[2*p + 1] = hn[1];
            wp[p] = pk_bf16(hn[0], hn[1]);      // early ds_write_b32, spreads drain
        }
        __syncthreads();
    };

    for (int t = 0; t < T_LEN; t += 2) {
        // ---- chunk refill: spill prefetched regs to LDS, then prefetch next ----
        if ((t & (CHUNK - 1)) == 0) {
            #pragma unroll
            for (int k4 = 0; k4 < 4; ++k4) {
                const int flat4 = k4 * 2048 + tid * 4;
                const int rem   = flat4 & 511;
                u32x2 two;
                two[0] = pk_bf16(xreg[k4][0], xreg[k4][1]);
                two[1] = pk_bf16(xreg[k4][2], xreg[k4][3]);
                *(u32x2*)&xlds[rem >> 4][(rem & 15) >> 3][flat4 >> 9][rem & 7] = two;
            }
            __syncthreads();
            const int tnext = (t + CHUNK < T_LEN) ? (t + CHUNK) : t;
            const float* xb = x + (size_t)b0 * (T_LEN * IN_DIM) + (size_t)tnext * IN_DIM;
            #pragma unroll
            for (int k4 = 0; k4 < 4; ++k4) {
                const int flat4 = k4 * 2048 + tid * 4;
                xreg[k4] = *(const f32x4*)(xb + (size_t)(flat4 >> 9) * (T_LEN * IN_DIM) + (flat4 & 511));
            }
        }
        const int s = t & (CHUNK - 1);
        step_fn(0, 1, s);
        step_fn(1, 0, s + 1);
    }

    // ---- epilogue: out[b] = sum_cols h * fc_w + fc_b ----
    float v = 0.0f;
    #pragma unroll
    for (int r = 0; r < 4; ++r)
        v = fmaf(hreg[r], fc_w[wv * 16 + quad * 4 + r], v);
    v += __shfl_xor(v, 16);
    v += __shfl_xor(v, 32);
    if (tid < 16) red[tid] = 0.0f;
    __syncthreads();
    if (lane < 16) atomicAdd(&red[c16], v);
    __syncthreads();
    if (tid < 16) out[b0 + tid] = red[tid] + fc_b[0];
}

extern "C" void kernel_launch(void* const* d_in, const int* in_sizes, int n_in,
                              void* d_out, int out_size, void* d_ws, size_t ws_size,
                              hipStream_t stream) {
    const float* x    = (const float*)d_in[0];
    const float* W_ih = (const float*)d_in[1];
    const float* W_hh = (const float*)d_in[2];
    const float* b_ih = (const float*)d_in[3];
    const float* b_hh = (const float*)d_in[4];
    const float* fc_w = (const float*)d_in[5];
    const float* fc_b = (const float*)d_in[6];
    float* out = (float*)d_out;

    slstm_persistent<<<64, 512, 0, stream>>>(x, W_ih, W_hh, b_ih, b_hh, fc_w, fc_b, out);
}

// Round 7
// 1806.600 us; speedup vs baseline: 8.8395x; 1.0081x over previous
//
#include <hip/hip_runtime.h>
#include <hip/hip_bf16.h>

// SLSTM recurrence + Linear.  B=1024, T=2048, IN=16, H=128, OUT=1.
// 64 persistent WGs x 512 thr; WG owns 16 batch rows for all T steps.
// gates^T (512x16) = W'(512x160) @ [h|x]^T via mfma_f32_16x16x32_bf16,
// A=pre-scaled weights in regs (exp2-ready args), bias rides MFMA C operand,
// h in LDS in fragment order (conflict-free b128 reads / b32 writes), dbuf.
// R7 vs R6:
//  (a) x LDS double-buffered, spill spread 1 dword/thread/iter (iters 0-7),
//      global prefetch at iter 8 -> no chunk-boundary burst/barrier;
//  (b) accNext: x-MFMA for step t+1 computed during step t (doesn't need h(t)),
//      post-barrier h-chain is 4 MFMAs deep starting from a ready C;
//  (c) gate-arg clamps dropped (|args| provably < 127); only ec clamp kept.
// Cycle model R6: step 2041 = 1274 VALU (trans 896 fixed) + 767 exposed.
// R3 lesson: cross-CU per-step exchange >= ~2000 cyc (MALL RTT) — 64 CUs is final.

#define T_LEN 2048
#define IN_DIM 16
#define CHUNK 32

typedef __attribute__((ext_vector_type(4))) float f32x4;
typedef __attribute__((ext_vector_type(2))) float f32x2;
typedef __attribute__((ext_vector_type(8))) short s16x8;
typedef __attribute__((ext_vector_type(4))) short s16x4;

__device__ __forceinline__ short f2bf(float f) {
    union { float f; unsigned u; } v; v.f = f;
    unsigned r = v.u + 0x7fffu + ((v.u >> 16) & 1u);   // RNE
    return (short)(r >> 16);
}

// pack two f32 -> two bf16 (RNE) in one dword
__device__ __forceinline__ unsigned pk_bf16(float a, float b) {
#if __has_builtin(__builtin_amdgcn_cvt_pk_bf16_f32)
    typedef __attribute__((ext_vector_type(2))) __bf16 bf16x2;
    bf16x2 r = __builtin_amdgcn_cvt_pk_bf16_f32(a, b);
    union { bf16x2 v; unsigned u; } c; c.v = r;
    return c.u;
#else
    return (unsigned)(unsigned short)f2bf(a) | ((unsigned)(unsigned short)f2bf(b) << 16);
#endif
}

__global__ __launch_bounds__(512, 2)
void slstm_persistent(const float* __restrict__ x,
                      const float* __restrict__ W_ih,
                      const float* __restrict__ W_hh,
                      const float* __restrict__ b_ih,
                      const float* __restrict__ b_hh,
                      const float* __restrict__ fc_w,
                      const float* __restrict__ fc_b,
                      float* __restrict__ out)
{
    // fragment-ordered h, double-buffered (16 KB)
    __shared__ __align__(16) unsigned short h_frag[2][4096];
    // x frags, DOUBLE-buffered: [buf][slot][qh][batch][j] (32 KB)
    __shared__ __align__(16) unsigned short xlds[2][CHUNK][2][16][8];
    __shared__ __align__(16) unsigned short xzero[8];
    __shared__ float red[16];

    const int tid  = threadIdx.x;
    const int lane = tid & 63;
    const int wv   = tid >> 6;          // wave 0..7
    const int c16  = lane & 15;         // batch row / D col
    const int quad = lane >> 4;         // 0..3
    const int b0   = blockIdx.x * 16;

    const float kNL2E = -1.44269504f;   // -log2(e)

    // ---- A-operand weights, pre-scaled so exp2 args come straight from MFMA ----
    s16x8 wfrag[4][5];                  // kf 0..3 = h frags, kf 4 = x
    f32x4 biasC[4];
    #pragma unroll
    for (int g = 0; g < 4; ++g) {
        const float scale = (g == 2) ? (2.0f * kNL2E) : kNL2E;
        const int n = g * 128 + wv * 16 + c16;
        #pragma unroll
        for (int kf = 0; kf < 5; ++kf) {
            s16x8 fr;
            #pragma unroll
            for (int j = 0; j < 8; ++j) {
                const int k = kf * 32 + quad * 8 + j;
                float v;
                if (kf < 4) v = W_hh[n * 128 + k];
                else {
                    const int kk = k - 128;
                    v = (kk < IN_DIM) ? W_ih[n * IN_DIM + kk] : 0.0f;
                }
                fr[j] = f2bf(v * scale);
            }
            wfrag[g][kf] = fr;
        }
        #pragma unroll
        for (int r = 0; r < 4; ++r) {
            const int m = g * 128 + wv * 16 + quad * 4 + r;
            biasC[g][r] = (b_ih[m] + b_hh[m]) * scale;
        }
    }

    for (int i = tid; i < 4096; i += 512) h_frag[0][i] = 0;   // h0 = 0
    if (tid < 8) xzero[tid] = 0;

    // writer position of this lane's 4 h values (cols wv*16+quad*4+r, batch c16)
    const int kfw   = wv >> 1;
    const int quadw = (wv & 1) * 2 + (quad >> 1);
    const int widx  = ((kfw * 4 + quadw) * 16 + c16) * 8 + (quad & 1) * 4;
    unsigned* const wp0 = (unsigned*)&h_frag[0][widx];
    unsigned* const wp1 = (unsigned*)&h_frag[1][widx];

    // x-frag read addressing: lane base + (buf,slot) offset (0 for quads 2,3)
    const bool xq = (quad < 2);
    const unsigned short* const xbase = xq ? &xlds[0][0][quad][c16][0] : xzero;
    const int xmask = xq ? ~0 : 0;      // applied to the (buf,slot) short-offset

    f32x2 c01 = {0.f, 0.f}, c23 = {0.f, 0.f};
    float hreg[4] = {0.f, 0.f, 0.f, 0.f};

    // ---- prime: chunk 0 burst-spilled to xlds[0]; chunk 1 into xreg ----
    f32x4 xreg[4];
    {
        const float* xb = x + (size_t)b0 * (T_LEN * IN_DIM);
        #pragma unroll
        for (int k4 = 0; k4 < 4; ++k4) {
            const int flat4 = k4 * 2048 + tid * 4;
            const int rem   = flat4 & 511;
            f32x4 v4 = *(const f32x4*)(xb + (size_t)(flat4 >> 9) * (T_LEN * IN_DIM) + rem);
            const int slot = rem >> 4, fb = rem & 15;
            unsigned* dst = (unsigned*)&xlds[0][slot][fb >> 3][flat4 >> 9][fb & 7];
            dst[0] = pk_bf16(v4[0], v4[1]);
            dst[1] = pk_bf16(v4[2], v4[3]);
        }
        const float* xb1 = xb + CHUNK * IN_DIM;
        #pragma unroll
        for (int k4 = 0; k4 < 4; ++k4) {
            const int flat4 = k4 * 2048 + tid * 4;
            xreg[k4] = *(const f32x4*)(xb1 + (size_t)(flat4 >> 9) * (T_LEN * IN_DIM) + (flat4 & 511));
        }
    }
    __syncthreads();

    const f32x2 kone = {1.f, 1.f};
    const f32x2 kn2l = {2.0f * kNL2E, 2.0f * kNL2E};

    // accNext = bias + x_t-MFMA, computed one step ahead
    f32x4 accN[4];
    {
        int off = 0 & xmask;            // t=0: buf 0, slot 0
        s16x8 zx0 = *(const s16x8*)(xbase + off);
        #pragma unroll
        for (int g = 0; g < 4; ++g)
            accN[g] = __builtin_amdgcn_mfma_f32_16x16x32_bf16(wfrag[g][4], zx0, biasC[g], 0, 0, 0);
    }

    // one timestep: h from buf RB -> h' into buf WB; also produce accN for t+1
    auto step_fn = [&](const int RB, const int WB, const int t) {
        // B-frags: h (conflict-free b128)
        s16x8 zf[4];
        #pragma unroll
        for (int kf = 0; kf < 4; ++kf)
            zf[kf] = *(const s16x8*)&h_frag[RB][(kf * 4 + quad) * 128 + c16 * 8];

        // 16 h-MFMAs chained on accN (bias + x already in)
        f32x4 acc[4];
        #pragma unroll
        for (int g = 0; g < 4; ++g)
            acc[g] = __builtin_amdgcn_mfma_f32_16x16x32_bf16(wfrag[g][0], zf[0], accN[g], 0, 0, 0);
        #pragma unroll
        for (int kf = 1; kf < 4; ++kf)
            #pragma unroll
            for (int g = 0; g < 4; ++g)
                acc[g] = __builtin_amdgcn_mfma_f32_16x16x32_bf16(wfrag[g][kf], zf[kf], acc[g], 0, 0, 0);

        // accN for step t+1: x-frag MFMA (independent of h(t))
        {
            const int ts   = t + 1;
            const int off  = (((ts >> 5) & 1) * (CHUNK * 2 * 16 * 8) + (ts & 31) * (2 * 16 * 8)) & xmask;
            s16x8 zxn = *(const s16x8*)(xbase + off);
            #pragma unroll
            for (int g = 0; g < 4; ++g)
                accN[g] = __builtin_amdgcn_mfma_f32_16x16x32_bf16(wfrag[g][4], zxn, biasC[g], 0, 0, 0);
        }

        // elementwise on f32x2 pairs; only the ec arg needs clamping
        // ei=e^{-i}, ef=e^{-f}, eg=e^{-2g}, eo=e^{-o}, ec=e^{-2c'}
        // c' = [c(1+ei)(1+eg) + (1-eg)(1+ef)] / [(1+ef)(1+ei)(1+eg)]
        // h  = (1-ec) / [(1+eo)(1+ec)]
        unsigned* wp = (WB == 0) ? wp0 : wp1;
        #pragma unroll
        for (int p = 0; p < 2; ++p) {
            f32x2 ei = {__builtin_amdgcn_exp2f(acc[0][2*p]), __builtin_amdgcn_exp2f(acc[0][2*p+1])};
            f32x2 ef = {__builtin_amdgcn_exp2f(acc[1][2*p]), __builtin_amdgcn_exp2f(acc[1][2*p+1])};
            f32x2 eg = {__builtin_amdgcn_exp2f(acc[2][2*p]), __builtin_amdgcn_exp2f(acc[2][2*p+1])};
            f32x2 eo = {__builtin_amdgcn_exp2f(acc[3][2*p]), __builtin_amdgcn_exp2f(acc[3][2*p+1])};

            f32x2 afv = kone + ef;
            f32x2 t1  = (kone + ei) * (kone + eg);
            f32x2 cpr = (p == 0) ? c01 : c23;
            f32x2 num = cpr * t1 + (kone - eg) * afv;
            f32x2 den = afv * t1;
            f32x2 rd  = {__builtin_amdgcn_rcpf(den[0]), __builtin_amdgcn_rcpf(den[1])};
            f32x2 cn  = num * rd;
            if (p == 0) c01 = cn; else c23 = cn;

            f32x2 eca = cn * kn2l;
            eca = {fminf(eca[0], 40.f), fminf(eca[1], 40.f)};
            f32x2 ec  = {__builtin_amdgcn_exp2f(eca[0]), __builtin_amdgcn_exp2f(eca[1])};
            f32x2 dh  = (kone + eo) * (kone + ec);
            f32x2 rh  = {__builtin_amdgcn_rcpf(dh[0]), __builtin_amdgcn_rcpf(dh[1])};
            f32x2 hn  = (kone - ec) * rh;
            hreg[2*p]     = hn[0];
            hreg[2*p + 1] = hn[1];
            wp[p] = pk_bf16(hn[0], hn[1]);      // early ds_write_b32
        }
        __syncthreads();
    };

    for (int t = 0; t < T_LEN; t += 2) {
        step_fn(0, 1, t);

        // ---- spread x maintenance (1 small op per iter) ----
        const int iter = (t >> 1) & 15;         // 0..15 within chunk
        const int cbase = t & ~(CHUNK - 1);     // chunk start
        if (iter < 8) {
            // spill chunk c+1 (held in xreg) into xlds[(c+1)&1], one dword
            if (cbase + CHUNK < T_LEN) {
                const int k4 = iter >> 1, half = iter & 1;
                const int flat4 = k4 * 2048 + tid * 4;
                const int rem   = flat4 & 511;
                const int slot = rem >> 4, fb = rem & 15;
                const int nb1 = ((cbase >> 5) + 1) & 1;
                unsigned* dst = (unsigned*)&xlds[nb1][slot][fb >> 3][flat4 >> 9][(fb & 7) + 2 * half];
                dst[0] = pk_bf16(xreg[k4][2 * half], xreg[k4][2 * half + 1]);
            }
        } else if (iter == 8) {
            // prefetch chunk c+2 into xreg
            const int tnext = cbase + 2 * CHUNK;
            if (tnext < T_LEN) {
                const float* xb = x + (size_t)b0 * (T_LEN * IN_DIM) + (size_t)tnext * IN_DIM;
                #pragma unroll
                for (int k4 = 0; k4 < 4; ++k4) {
                    const int flat4 = k4 * 2048 + tid * 4;
                    xreg[k4] = *(const f32x4*)(xb + (size_t)(flat4 >> 9) * (T_LEN * IN_DIM) + (flat4 & 511));
                }
            }
        }

        step_fn(1, 0, t + 1);
    }

    // ---- epilogue: out[b] = sum_cols h * fc_w + fc_b ----
    float v = 0.0f;
    #pragma unroll
    for (int r = 0; r < 4; ++r)
        v = fmaf(hreg[r], fc_w[wv * 16 + quad * 4 + r], v);
    v += __shfl_xor(v, 16);
    v += __shfl_xor(v, 32);
    if (tid < 16) red[tid] = 0.0f;
    __syncthreads();
    if (lane < 16) atomicAdd(&red[c16], v);
    __syncthreads();
    if (tid < 16) out[b0 + tid] = red[tid] + fc_b[0];
}

extern "C" void kernel_launch(void* const* d_in, const int* in_sizes, int n_in,
                              void* d_out, int out_size, void* d_ws, size_t ws_size,
                              hipStream_t stream) {
    const float* x    = (const float*)d_in[0];
    const float* W_ih = (const float*)d_in[1];
    const float* W_hh = (const float*)d_in[2];
    const float* b_ih = (const float*)d_in[3];
    const float* b_hh = (const float*)d_in[4];
    const float* fc_w = (const float*)d_in[5];
    const float* fc_b = (const float*)d_in[6];
    float* out = (float*)d_out;

    slstm_persistent<<<64, 512, 0, stream>>>(x, W_ih, W_hh, b_ih, b_hh, fc_w, fc_b, out);
}

// Round 8
// 1568.821 us; speedup vs baseline: 10.1793x; 1.1516x over previous
//
#include <hip/hip_runtime.h>
#include <hip/hip_bf16.h>

// SLSTM recurrence + Linear.  B=1024, T=2048, IN=16, H=128, OUT=1.
// R8: 128 WGs x 256 thr (4 waves = 1 wave/SIMD), WG owns 8 batch rows -> 128 CUs,
// zero cross-CU communication (R3 lesson: cross-CU sync = HBM RTT, dead).
// Each wave owns 2 col-groups x 4 gates = 8 M-tiles (N=8 valid cols of 16).
// After gate MFMAs, the two half-filled accs are PACKED into one lane-dense tile
// via v_update_dpp row_ror:8 bank_mask:0xC (1 instr/f32) -> elementwise runs at
// 28 trans-instr/wave x 1 wave/SIMD = 448 cyc/SIMD (halved vs R7's 896).
// Weights pre-scaled (exp2-ready), bias rides MFMA C, accN (x-MFMA) one step
// ahead, h in LDS fragment order (conflict-free b128 reads), x dbuf + spread spill.

#define T_LEN 2048
#define IN_DIM 16
#define CHUNK 32
#define NROWS 8

typedef __attribute__((ext_vector_type(4))) float f32x4;
typedef __attribute__((ext_vector_type(2))) float f32x2;
typedef __attribute__((ext_vector_type(8))) short s16x8;
typedef __attribute__((ext_vector_type(2))) unsigned u32x2;

__device__ __forceinline__ short f2bf(float f) {
    union { float f; unsigned u; } v; v.f = f;
    unsigned r = v.u + 0x7fffu + ((v.u >> 16) & 1u);   // RNE
    return (short)(r >> 16);
}
__device__ __forceinline__ unsigned pk_bf16(float a, float b) {
#if __has_builtin(__builtin_amdgcn_cvt_pk_bf16_f32)
    typedef __attribute__((ext_vector_type(2))) __bf16 bf16x2;
    bf16x2 r = __builtin_amdgcn_cvt_pk_bf16_f32(a, b);
    union { bf16x2 v; unsigned u; } c; c.v = r;
    return c.u;
#else
    return (unsigned)(unsigned short)f2bf(a) | ((unsigned)(unsigned short)f2bf(b) << 16);
#endif
}
// lanes 0-7 of each 16-lane row keep a; lanes 8-15 get b's lanes 0-7 (row_ror:8,
// bank_mask 0xC updates only banks 2,3 = lanes 8-15 of each row)
__device__ __forceinline__ float pack_hi8(float a, float b) {
    return __int_as_float(__builtin_amdgcn_update_dpp(
        __float_as_int(a), __float_as_int(b), 0x128, 0xF, 0xC, false));
}

__global__ __launch_bounds__(256, 1)
void slstm_persistent(const float* __restrict__ x,
                      const float* __restrict__ W_ih,
                      const float* __restrict__ W_hh,
                      const float* __restrict__ b_ih,
                      const float* __restrict__ b_hh,
                      const float* __restrict__ fc_w,
                      const float* __restrict__ fc_b,
                      float* __restrict__ out)
{
    // h frags: [kf 0..3][quadf][n 16][j 8] bf16, dbuf (rows n>=8 stay zero)
    __shared__ __align__(16) unsigned short h_frag[2][4096];        // 16 KB
    __shared__ __align__(16) unsigned short xlds[2][CHUNK][2][16][8]; // 32 KB
    __shared__ __align__(16) unsigned short xzero[8];
    __shared__ float red[NROWS];

    const int tid  = threadIdx.x;
    const int lane = tid & 63;
    const int wv   = tid >> 6;          // wave 0..3
    const int c16  = lane & 15;
    const int quad = lane >> 4;         // 0..3
    const int b0   = blockIdx.x * NROWS;

    const float kNL2E = -1.44269504f;

    // ---- weights pre-scaled; wave owns col-groups {2wv, 2wv+1} x 4 gates ----
    s16x8 wfrag[2][4][5];               // [s][g][kf], kf4 = x
    f32x4 biasC[2][4];
    #pragma unroll
    for (int s = 0; s < 2; ++s) {
        #pragma unroll
        for (int g = 0; g < 4; ++g) {
            const float scale = (g == 2) ? (2.0f * kNL2E) : kNL2E;
            const int n = g * 128 + (2 * wv + s) * 16 + c16;
            #pragma unroll
            for (int kf = 0; kf < 5; ++kf) {
                s16x8 fr;
                #pragma unroll
                for (int j = 0; j < 8; ++j) {
                    const int k = kf * 32 + quad * 8 + j;
                    float v;
                    if (kf < 4) v = W_hh[n * 128 + k];
                    else {
                        const int kk = k - 128;
                        v = (kk < IN_DIM) ? W_ih[n * IN_DIM + kk] : 0.0f;
                    }
                    fr[j] = f2bf(v * scale);
                }
                wfrag[s][g][kf] = fr;
            }
            #pragma unroll
            for (int r = 0; r < 4; ++r) {
                const int m = g * 128 + (2 * wv + s) * 16 + quad * 4 + r;
                biasC[s][g][r] = (b_ih[m] + b_hh[m]) * scale;
            }
        }
    }

    // ---- zero LDS (h both bufs incl. n>=8; x both bufs incl. n>=8) ----
    for (int i = tid; i < 4096; i += 256) ((unsigned*)h_frag)[i] = 0;     // 16 KB
    for (int i = tid; i < 8192; i += 256) ((unsigned*)xlds)[i] = 0;       // 32 KB
    if (tid < 8) xzero[tid] = 0;

    // packed lane identity: col-group G, batch row n
    const int G  = 2 * wv + (c16 >> 3);
    const int nb = c16 & 7;
    // h-write position: cols k0..k0+3, row nb
    const int k0 = G * 16 + quad * 4;
    const int waddr = (((k0 >> 5) * 4 + ((k0 >> 3) & 3)) * 16 + nb) * 8 + (k0 & 7);

    // x-frag addressing (quads 2,3 read zeros)
    const bool xq = (quad < 2);
    const unsigned short* const xbase = xq ? &xlds[0][0][quad][c16][0] : xzero;
    const int xmask = xq ? ~0 : 0;

    f32x2 c01 = {0.f, 0.f}, c23 = {0.f, 0.f};
    float hreg[4] = {0.f, 0.f, 0.f, 0.f};

    // ---- prime: chunk 0 -> xlds[0]; chunk 1 -> xreg ----
    f32x4 xreg[4];
    {
        const float* xb = x + (size_t)b0 * (T_LEN * IN_DIM);
        #pragma unroll
        for (int k4 = 0; k4 < 4; ++k4) {
            const int flat4 = k4 * 1024 + tid * 4;
            const int rem   = flat4 & 511;
            f32x4 v4 = *(const f32x4*)(xb + (size_t)(flat4 >> 9) * (T_LEN * IN_DIM) + rem);
            unsigned* dst = (unsigned*)&xlds[0][rem >> 4][(rem & 15) >> 3][flat4 >> 9][rem & 7];
            dst[0] = pk_bf16(v4[0], v4[1]);
            dst[1] = pk_bf16(v4[2], v4[3]);
        }
        const float* xb1 = xb + CHUNK * IN_DIM;
        #pragma unroll
        for (int k4 = 0; k4 < 4; ++k4) {
            const int flat4 = k4 * 1024 + tid * 4;
            xreg[k4] = *(const f32x4*)(xb1 + (size_t)(flat4 >> 9) * (T_LEN * IN_DIM) + (flat4 & 511));
        }
    }
    __syncthreads();

    const f32x2 kone = {1.f, 1.f};
    const f32x2 kn2l = {2.0f * kNL2E, 2.0f * kNL2E};

    // accN = bias + x-MFMA, one step ahead
    f32x4 accN[2][4];
    {
        s16x8 zx0 = *(const s16x8*)(xbase + (0 & xmask));
        #pragma unroll
        for (int s = 0; s < 2; ++s)
            #pragma unroll
            for (int g = 0; g < 4; ++g)
                accN[s][g] = __builtin_amdgcn_mfma_f32_16x16x32_bf16(wfrag[s][g][4], zx0, biasC[s][g], 0, 0, 0);
    }

    auto step_fn = [&](const int RB, const int WB, const int t) {
        s16x8 zf[4];
        #pragma unroll
        for (int kf = 0; kf < 4; ++kf)
            zf[kf] = *(const s16x8*)&h_frag[RB][(kf * 4 + quad) * 128 + c16 * 8];

        // 32 h-MFMAs (8 independent chains of depth 4, C = accN)
        f32x4 acc[2][4];
        #pragma unroll
        for (int s = 0; s < 2; ++s)
            #pragma unroll
            for (int g = 0; g < 4; ++g)
                acc[s][g] = __builtin_amdgcn_mfma_f32_16x16x32_bf16(wfrag[s][g][0], zf[0], accN[s][g], 0, 0, 0);
        #pragma unroll
        for (int kf = 1; kf < 4; ++kf)
            #pragma unroll
            for (int s = 0; s < 2; ++s)
                #pragma unroll
                for (int g = 0; g < 4; ++g)
                    acc[s][g] = __builtin_amdgcn_mfma_f32_16x16x32_bf16(wfrag[s][g][kf], zf[kf], acc[s][g], 0, 0, 0);

        // accN for t+1 (x-frag independent of h(t))
        {
            const int ts  = t + 1;
            const int off = (((ts >> 5) & 1) * 8192 + (ts & 31) * 256) & xmask;
            s16x8 zxn = *(const s16x8*)(xbase + off);
            #pragma unroll
            for (int s = 0; s < 2; ++s)
                #pragma unroll
                for (int g = 0; g < 4; ++g)
                    accN[s][g] = __builtin_amdgcn_mfma_f32_16x16x32_bf16(wfrag[s][g][4], zxn, biasC[s][g], 0, 0, 0);
        }

        // pack 2 half-tiles -> 1 lane-dense tile (16 update_dpp)
        f32x4 pk[4];
        #pragma unroll
        for (int g = 0; g < 4; ++g)
            #pragma unroll
            for (int r = 0; r < 4; ++r)
                pk[g][r] = pack_hi8(acc[0][g][r], acc[1][g][r]);

        // elementwise (dense lanes): 5 exp2 + 2 rcp per element
        unsigned short* wp = &h_frag[WB][waddr];
        u32x2 hw;
        #pragma unroll
        for (int p = 0; p < 2; ++p) {
            f32x2 ei = {__builtin_amdgcn_exp2f(pk[0][2*p]), __builtin_amdgcn_exp2f(pk[0][2*p+1])};
            f32x2 ef = {__builtin_amdgcn_exp2f(pk[1][2*p]), __builtin_amdgcn_exp2f(pk[1][2*p+1])};
            f32x2 eg = {__builtin_amdgcn_exp2f(pk[2][2*p]), __builtin_amdgcn_exp2f(pk[2][2*p+1])};
            f32x2 eo = {__builtin_amdgcn_exp2f(pk[3][2*p]), __builtin_amdgcn_exp2f(pk[3][2*p+1])};

            f32x2 afv = kone + ef;
            f32x2 t1  = (kone + ei) * (kone + eg);
            f32x2 cpr = (p == 0) ? c01 : c23;
            f32x2 num = cpr * t1 + (kone - eg) * afv;
            f32x2 den = afv * t1;
            f32x2 rd  = {__builtin_amdgcn_rcpf(den[0]), __builtin_amdgcn_rcpf(den[1])};
            f32x2 cn  = num * rd;
            if (p == 0) c01 = cn; else c23 = cn;

            f32x2 eca = cn * kn2l;
            eca = {fminf(eca[0], 40.f), fminf(eca[1], 40.f)};
            f32x2 ec  = {__builtin_amdgcn_exp2f(eca[0]), __builtin_amdgcn_exp2f(eca[1])};
            f32x2 dh  = (kone + eo) * (kone + ec);
            f32x2 rh  = {__builtin_amdgcn_rcpf(dh[0]), __builtin_amdgcn_rcpf(dh[1])};
            f32x2 hn  = (kone - ec) * rh;
            hreg[2*p]     = hn[0];
            hreg[2*p + 1] = hn[1];
            hw[p] = pk_bf16(hn[0], hn[1]);
        }
        *(u32x2*)wp = hw;                       // one ds_write_b64 (cols k0..k0+3)
        __syncthreads();
    };

    for (int t = 0; t < T_LEN; t += 2) {
        step_fn(0, 1, t);

        const int iter  = (t >> 1) & 15;
        const int cbase = t & ~(CHUNK - 1);
        if (iter < 8) {
            if (cbase + CHUNK < T_LEN) {
                const int k4 = iter >> 1, half = iter & 1;
                const int flat4 = k4 * 1024 + tid * 4;
                const int rem   = flat4 & 511;
                const int nb1 = ((cbase >> 5) + 1) & 1;
                unsigned* dst = (unsigned*)&xlds[nb1][rem >> 4][(rem & 15) >> 3][flat4 >> 9][(rem & 7) + 2 * half];
                dst[0] = pk_bf16(xreg[k4][2 * half], xreg[k4][2 * half + 1]);
            }
        } else if (iter == 8) {
            const int tnext = cbase + 2 * CHUNK;
            if (tnext < T_LEN) {
                const float* xb = x + (size_t)b0 * (T_LEN * IN_DIM) + (size_t)tnext * IN_DIM;
                #pragma unroll
                for (int k4 = 0; k4 < 4; ++k4) {
                    const int flat4 = k4 * 1024 + tid * 4;
                    xreg[k4] = *(const f32x4*)(xb + (size_t)(flat4 >> 9) * (T_LEN * IN_DIM) + (flat4 & 511));
                }
            }
        }

        step_fn(1, 0, t + 1);
    }

    // ---- epilogue: out[b] = sum_cols h * fc_w + fc_b ----
    float v = 0.0f;
    #pragma unroll
    for (int r = 0; r < 4; ++r)
        v = fmaf(hreg[r], fc_w[G * 16 + quad * 4 + r], v);
    v += __shfl_xor(v, 8);                      // other col-group, same batch
    v += __shfl_xor(v, 16);
    v += __shfl_xor(v, 32);                     // quads
    if (tid < NROWS) red[tid] = 0.0f;
    __syncthreads();
    if (lane < NROWS) atomicAdd(&red[nb], v);   // 4 waves combine (lanes 0-7)
    __syncthreads();
    if (tid < NROWS) out[b0 + tid] = red[tid] + fc_b[0];
}

extern "C" void kernel_launch(void* const* d_in, const int* in_sizes, int n_in,
                              void* d_out, int out_size, void* d_ws, size_t ws_size,
                              hipStream_t stream) {
    const float* x    = (const float*)d_in[0];
    const float* W_ih = (const float*)d_in[1];
    const float* W_hh = (const float*)d_in[2];
    const float* b_ih = (const float*)d_in[3];
    const float* b_hh = (const float*)d_in[4];
    const float* fc_w = (const float*)d_in[5];
    const float* fc_b = (const float*)d_in[6];
    float* out = (float*)d_out;

    slstm_persistent<<<128, 256, 0, stream>>>(x, W_ih, W_hh, b_ih, b_hh, fc_w, fc_b, out);
}

// Round 10
// 1279.133 us; speedup vs baseline: 12.4846x; 1.2265x over previous
//
#include <hip/hip_runtime.h>
#include <hip/hip_bf16.h>

// SLSTM recurrence + Linear.  B=1024, T=2048, IN=16, H=128, OUT=1.
// R10 = R9 with the pack4 DPP rotation fix.
// DPP semantics (verified via AMD cross-lane blog scan + LLVM AtomicOptimizer):
//   row_shr:n -> dst[i] = src[i-n];  row_ror:n -> dst[i] = src[(i-n) mod 16].
// R9 assumed the opposite; ror:8 is self-symmetric (worked in R8), the
// asymmetric ror:4/12 swapped e=1 and e=3 -> half of h garbage, absmax 0.44.
// Structure: 256 WGs x 512 thr (8 waves = 2/SIMD), 4 batch rows per WG ->
// all 256 CUs, zero cross-CU communication. Wave owns col-group wv x 4 gates
// = 4 M-tiles, N=4 valid batch cols; gate accs packed 4->1 lane-dense via
// 3-dpp chain; 1 element/lane -> 7 trans instr/wave. h in LDS fragment order
// (dbuf); x staged as bf16 frags (dbuf, spread spill + chunk-ahead prefetch);
// weights pre-scaled (exp2-ready); bias + x-MFMA ride accN one step ahead.

#define T_LEN 2048
#define IN_DIM 16
#define CHUNK 32
#define NROWS 4

typedef __attribute__((ext_vector_type(4))) float f32x4;
typedef __attribute__((ext_vector_type(8))) short s16x8;

__device__ __forceinline__ short f2bf(float f) {
    union { float f; unsigned u; } v; v.f = f;
    unsigned r = v.u + 0x7fffu + ((v.u >> 16) & 1u);   // RNE
    return (short)(r >> 16);
}
__device__ __forceinline__ unsigned pk_bf16(float a, float b) {
#if __has_builtin(__builtin_amdgcn_cvt_pk_bf16_f32)
    typedef __attribute__((ext_vector_type(2))) __bf16 bf16x2;
    bf16x2 r = __builtin_amdgcn_cvt_pk_bf16_f32(a, b);
    union { bf16x2 v; unsigned u; } c; c.v = r;
    return c.u;
#else
    return (unsigned)(unsigned short)f2bf(a) | ((unsigned)(unsigned short)f2bf(b) << 16);
#endif
}
// merge quarter-dense regs: lanes 0-3 keep r0; 4-7 <- r1[0-3]; 8-11 <- r2[0-3];
// 12-15 <- r3[0-3].  row_ror:n pulls from lane (i-n) mod 16.
__device__ __forceinline__ float pack4(float r0, float r1, float r2, float r3) {
    int d = __float_as_int(r0);
    d = __builtin_amdgcn_update_dpp(d, __float_as_int(r1), 0x124, 0xF, 0x2, false); // ror:4  -> lanes 4-7
    d = __builtin_amdgcn_update_dpp(d, __float_as_int(r2), 0x128, 0xF, 0x4, false); // ror:8  -> lanes 8-11
    d = __builtin_amdgcn_update_dpp(d, __float_as_int(r3), 0x12C, 0xF, 0x8, false); // ror:12 -> lanes 12-15
    return __int_as_float(d);
}

__global__ __launch_bounds__(512, 2)
void slstm_persistent(const float* __restrict__ x,
                      const float* __restrict__ W_ih,
                      const float* __restrict__ W_hh,
                      const float* __restrict__ b_ih,
                      const float* __restrict__ b_hh,
                      const float* __restrict__ fc_w,
                      const float* __restrict__ fc_b,
                      float* __restrict__ out)
{
    // h frags [16 kq][16 n][8 j] bf16, dbuf (8 KB); only n<4 carries data
    __shared__ __align__(16) unsigned short h_frag[2][2048];
    // x frags [buf][slot][qh 2][n 4][j 8] bf16, dbuf (8 KB)
    __shared__ __align__(16) unsigned short xlds[2][CHUNK][2][4][8];
    __shared__ float red[NROWS];

    const int tid  = threadIdx.x;
    const int lane = tid & 63;
    const int wv   = tid >> 6;          // wave 0..7 = col-group
    const int c16  = lane & 15;
    const int quad = lane >> 4;         // 0..3
    const int b0   = blockIdx.x * NROWS;

    const float kNL2E = -1.44269504f;

    // ---- weights pre-scaled; wave owns col-group wv x 4 gates ----
    s16x8 wfrag[4][5];                  // [g][kf], kf4 = x
    f32x4 biasC[4];
    #pragma unroll
    for (int g = 0; g < 4; ++g) {
        const float scale = (g == 2) ? (2.0f * kNL2E) : kNL2E;
        const int n = g * 128 + wv * 16 + c16;
        #pragma unroll
        for (int kf = 0; kf < 5; ++kf) {
            s16x8 fr;
            #pragma unroll
            for (int j = 0; j < 8; ++j) {
                const int k = kf * 32 + quad * 8 + j;
                float v;
                if (kf < 4) v = W_hh[n * 128 + k];
                else {
                    const int kk = k - 128;
                    v = (kk < IN_DIM) ? W_ih[n * IN_DIM + kk] : 0.0f;
                }
                fr[j] = f2bf(v * scale);
            }
            wfrag[g][kf] = fr;
        }
        #pragma unroll
        for (int r = 0; r < 4; ++r) {
            const int m = g * 128 + wv * 16 + quad * 4 + r;
            biasC[g][r] = (b_ih[m] + b_hh[m]) * scale;
        }
    }

    // zero h buf 0 (h0 = 0); buf 1 fully written at t=0 before first read
    for (int i = tid; i < 1024; i += 512) ((unsigned*)h_frag)[i] = 0;

    // ---- packed-lane identity: element (col, nb) ----
    const int e    = c16 >> 2;                          // 0..3
    const int nb   = c16 & 3;                           // batch row
    const int col  = wv * 16 + quad * 4 + e;            // h column
    const int waddr = ((col >> 3) * 16 + nb) * 8 + (col & 7);   // shorts
    // h-frag read: valid lanes c16<4 read their data; others broadcast addr 0
    const int hoff = (c16 < 4) ? (quad * 256 + c16 * 16) : 0;   // bytes
    // x-frag read: valid lanes quad<2 && c16<4
    const bool xv = (quad < 2) && (c16 < 4);
    const int xoff  = xv ? (quad * 64 + c16 * 16) : 0;          // bytes
    const int xmask = xv ? ~0 : 0;

    float c_st = 0.0f, h_ep = 0.0f;

    // ---- prologue: stage chunk 0 -> xlds[0]; chunk 1 -> xreg ----
    f32x4 xreg;
    {
        const int flat4 = tid * 4;
        const int b_loc = flat4 >> 9;
        const int rem   = flat4 & 511;
        const float* xr = x + (size_t)(b0 + b_loc) * (T_LEN * IN_DIM);
        f32x4 v4 = *(const f32x4*)(xr + rem);
        const int slot = rem >> 4, feat = rem & 15;
        unsigned* dst = (unsigned*)&xlds[0][slot][feat >> 3][b_loc][feat & 7];
        dst[0] = pk_bf16(v4[0], v4[1]);
        dst[1] = pk_bf16(v4[2], v4[3]);
        xreg = *(const f32x4*)(xr + CHUNK * IN_DIM + rem);
    }
    __syncthreads();

    // accN = bias + x-MFMA, one step ahead
    f32x4 accN[4];
    {
        s16x8 zx0 = *(const s16x8*)((const char*)xlds + (xoff & xmask));
        #pragma unroll
        for (int g = 0; g < 4; ++g)
            accN[g] = __builtin_amdgcn_mfma_f32_16x16x32_bf16(wfrag[g][4], zx0, biasC[g], 0, 0, 0);
    }

    auto step_fn = [&](const int RB, const int WB, const int t) {
        const char* hb = (const char*)h_frag[RB];
        s16x8 zf[4];
        #pragma unroll
        for (int kf = 0; kf < 4; ++kf)
            zf[kf] = *(const s16x8*)(hb + hoff + kf * 1024);

        // 16 h-MFMAs: 4 chains of depth 4, C = accN (bias + x already in)
        f32x4 acc[4];
        #pragma unroll
        for (int g = 0; g < 4; ++g)
            acc[g] = __builtin_amdgcn_mfma_f32_16x16x32_bf16(wfrag[g][0], zf[0], accN[g], 0, 0, 0);
        #pragma unroll
        for (int kf = 1; kf < 4; ++kf)
            #pragma unroll
            for (int g = 0; g < 4; ++g)
                acc[g] = __builtin_amdgcn_mfma_f32_16x16x32_bf16(wfrag[g][kf], zf[kf], acc[g], 0, 0, 0);

        // accN for t+1 (x-frag independent of h(t))
        {
            const int ts  = t + 1;
            const int off = (((ts >> 5) & 1) * 4096 + (ts & 31) * 128 + xoff) & xmask;
            s16x8 zxn = *(const s16x8*)((const char*)xlds + off);
            #pragma unroll
            for (int g = 0; g < 4; ++g)
                accN[g] = __builtin_amdgcn_mfma_f32_16x16x32_bf16(wfrag[g][4], zxn, biasC[g], 0, 0, 0);
        }

        // pack 4 quarter-dense regs -> 1 dense per gate (3 dpp each)
        const float di = pack4(acc[0][0], acc[0][1], acc[0][2], acc[0][3]);
        const float df = pack4(acc[1][0], acc[1][1], acc[1][2], acc[1][3]);
        const float dg = pack4(acc[2][0], acc[2][1], acc[2][2], acc[2][3]);
        const float dojj = pack4(acc[3][0], acc[3][1], acc[3][2], acc[3][3]);

        // scalar elementwise (1 element/lane): 5 exp2 + 2 rcp
        // ei=e^{-i}, ef=e^{-f}, eg=e^{-2g}, eo=e^{-o}, ec=e^{-2c'}
        const float ei = __builtin_amdgcn_exp2f(di);
        const float ef = __builtin_amdgcn_exp2f(df);
        const float eg = __builtin_amdgcn_exp2f(dg);
        const float eo = __builtin_amdgcn_exp2f(dojj);
        const float af = 1.0f + ef;
        const float t1 = (1.0f + ei) * (1.0f + eg);
        const float num = fmaf(c_st, t1, (1.0f - eg) * af);
        const float cn  = num * __builtin_amdgcn_rcpf(af * t1);
        c_st = cn;
        const float ec = __builtin_amdgcn_exp2f(fminf(cn * (2.0f * kNL2E), 40.f));
        const float hn = (1.0f - ec) * __builtin_amdgcn_rcpf((1.0f + eo) * (1.0f + ec));
        h_ep = hn;
        h_frag[WB][waddr] = (unsigned short)f2bf(hn);   // one ds_write_b16
        __syncthreads();
    };

    for (int t = 0; t < T_LEN; t += 2) {
        step_fn(0, 1, t);

        // ---- spread x maintenance ----
        const int iter  = (t >> 1) & 15;
        const int cbase = t & ~(CHUNK - 1);
        if (iter < 2) {
            // spill chunk c+1 (in xreg) into xlds[(c+1)&1], one dword/iter
            if (cbase + CHUNK < T_LEN) {
                const int flat4 = tid * 4;
                const int b_loc = flat4 >> 9;
                const int rem   = flat4 & 511;
                const int slot = rem >> 4, feat = rem & 15;
                const int nb1 = ((cbase >> 5) + 1) & 1;
                unsigned* dst = (unsigned*)&xlds[nb1][slot][feat >> 3][b_loc][(feat & 7) + 2 * iter];
                dst[0] = pk_bf16(xreg[2 * iter], xreg[2 * iter + 1]);
            }
        } else if (iter == 8) {
            // prefetch chunk c+2
            const int tnext = cbase + 2 * CHUNK;
            if (tnext < T_LEN) {
                const int flat4 = tid * 4;
                const int b_loc = flat4 >> 9;
                const int rem   = flat4 & 511;
                xreg = *(const f32x4*)(x + (size_t)(b0 + b_loc) * (T_LEN * IN_DIM)
                                         + (size_t)tnext * IN_DIM + rem);
            }
        }

        step_fn(1, 0, t + 1);
    }

    // ---- epilogue: out[b] = sum_cols h * fc_w + fc_b ----
    float v = h_ep * fc_w[col];
    v += __shfl_xor(v, 4);
    v += __shfl_xor(v, 8);                      // 4 e-groups (same nb)
    v += __shfl_xor(v, 16);
    v += __shfl_xor(v, 32);                     // quads
    if (tid < NROWS) red[tid] = 0.0f;
    __syncthreads();
    if (lane < NROWS) atomicAdd(&red[nb], v);   // 8 waves combine
    __syncthreads();
    if (tid < NROWS) out[b0 + tid] = red[tid] + fc_b[0];
}

extern "C" void kernel_launch(void* const* d_in, const int* in_sizes, int n_in,
                              void* d_out, int out_size, void* d_ws, size_t ws_size,
                              hipStream_t stream) {
    const float* x    = (const float*)d_in[0];
    const float* W_ih = (const float*)d_in[1];
    const float* W_hh = (const float*)d_in[2];
    const float* b_ih = (const float*)d_in[3];
    const float* b_hh = (const float*)d_in[4];
    const float* fc_w = (const float*)d_in[5];
    const float* fc_b = (const float*)d_in[6];
    float* out = (float*)d_out;

    slstm_persistent<<<256, 512, 0, stream>>>(x, W_ih, W_hh, b_ih, b_hh, fc_w, fc_b, out);
}

// Round 11
// 1255.376 us; speedup vs baseline: 12.7209x; 1.0189x over previous
//
#include <hip/hip_runtime.h>
#include <hip/hip_bf16.h>

// SLSTM recurrence + Linear.  B=1024, T=2048, IN=16, H=128, OUT=1.
// R11 = R10 + (a) conflict-free h LDS layout, (b) interleaved gate-chain /
// elementwise scheduling to overlap VALU tail under the MFMA pipe.
// Structure: 256 WGs x 512 thr (8 waves = 2/SIMD), 4 batch rows/WG, all 256
// CUs, zero cross-CU traffic. Wave owns col-group wv x 4 gates (4 M-tiles,
// N=4 fill); accs packed 4->1 lane-dense via 3-dpp chain (row_ror pulls from
// lane (i-n) mod 16 — verified R10); 1 elem/lane, 7 trans.
// Cycle model (R10 measured): step 1543 = MFMA pipe 721 (16 cyc/instr/SIMD,
// 40 instr = 640 floor, invariant in rows/WG) + VALU 611 + LDS ~200, fully
// SERIALIZED. R11 kills the 4-way h-read conflicts (R10 layout had quad
// stride 256B = 0 mod 128 dwords -> 16 lanes on banks 0-15) with a frag
// layout where the 16 valid lanes tile all 32 banks 2-way (free), and
// issues pack/exp2 for gates i,f,g while gates g2,g3 + accN still occupy
// the matrix pipe (tail-hiding). MFMA floor ~546 us; fp8 h breaks tolerance.

#define T_LEN 2048
#define IN_DIM 16
#define CHUNK 32
#define NROWS 4

typedef __attribute__((ext_vector_type(4))) float f32x4;
typedef __attribute__((ext_vector_type(8))) short s16x8;

__device__ __forceinline__ short f2bf(float f) {
    union { float f; unsigned u; } v; v.f = f;
    unsigned r = v.u + 0x7fffu + ((v.u >> 16) & 1u);   // RNE
    return (short)(r >> 16);
}
__device__ __forceinline__ unsigned pk_bf16(float a, float b) {
#if __has_builtin(__builtin_amdgcn_cvt_pk_bf16_f32)
    typedef __attribute__((ext_vector_type(2))) __bf16 bf16x2;
    bf16x2 r = __builtin_amdgcn_cvt_pk_bf16_f32(a, b);
    union { bf16x2 v; unsigned u; } c; c.v = r;
    return c.u;
#else
    return (unsigned)(unsigned short)f2bf(a) | ((unsigned)(unsigned short)f2bf(b) << 16);
#endif
}
// merge quarter-dense regs: lanes 0-3 keep r0; 4-7 <- r1[0-3]; 8-11 <- r2[0-3];
// 12-15 <- r3[0-3].  row_ror:n pulls from lane (i-n) mod 16 (verified R10).
__device__ __forceinline__ float pack4(float r0, float r1, float r2, float r3) {
    int d = __float_as_int(r0);
    d = __builtin_amdgcn_update_dpp(d, __float_as_int(r1), 0x124, 0xF, 0x2, false);
    d = __builtin_amdgcn_update_dpp(d, __float_as_int(r2), 0x128, 0xF, 0x4, false);
    d = __builtin_amdgcn_update_dpp(d, __float_as_int(r3), 0x12C, 0xF, 0x8, false);
    return __int_as_float(d);
}

__global__ __launch_bounds__(512, 2)
void slstm_persistent(const float* __restrict__ x,
                      const float* __restrict__ W_ih,
                      const float* __restrict__ W_hh,
                      const float* __restrict__ b_ih,
                      const float* __restrict__ b_hh,
                      const float* __restrict__ fc_w,
                      const float* __restrict__ fc_b,
                      float* __restrict__ out)
{
    // h: element (col, nb) at shorts[(col>>5)*128 + ((col>>3)&3)*32 + nb*8 + (col&7)]
    // = frag-ordered for the B-operand; the 16 valid reader lanes (v=quad*4+c16,
    // 16B each) span 256B = all 32 banks exactly twice -> conflict-free. 1 KB/buf.
    __shared__ __align__(16) unsigned short h_frag[2][512];
    // x frags [buf][slot][qh 2][n 4][j 8] bf16, dbuf (8 KB)
    __shared__ __align__(16) unsigned short xlds[2][CHUNK][2][4][8];
    __shared__ float red[NROWS];

    const int tid  = threadIdx.x;
    const int lane = tid & 63;
    const int wv   = tid >> 6;          // wave 0..7 = col-group
    const int c16  = lane & 15;
    const int quad = lane >> 4;         // 0..3
    const int b0   = blockIdx.x * NROWS;

    const float kNL2E = -1.44269504f;

    // ---- weights pre-scaled; wave owns col-group wv x 4 gates ----
    s16x8 wfrag[4][5];                  // [g][kf], kf4 = x
    f32x4 biasC[4];
    #pragma unroll
    for (int g = 0; g < 4; ++g) {
        const float scale = (g == 2) ? (2.0f * kNL2E) : kNL2E;
        const int n = g * 128 + wv * 16 + c16;
        #pragma unroll
        for (int kf = 0; kf < 5; ++kf) {
            s16x8 fr;
            #pragma unroll
            for (int j = 0; j < 8; ++j) {
                const int k = kf * 32 + quad * 8 + j;
                float v;
                if (kf < 4) v = W_hh[n * 128 + k];
                else {
                    const int kk = k - 128;
                    v = (kk < IN_DIM) ? W_ih[n * IN_DIM + kk] : 0.0f;
                }
                fr[j] = f2bf(v * scale);
            }
            wfrag[g][kf] = fr;
        }
        #pragma unroll
        for (int r = 0; r < 4; ++r) {
            const int m = g * 128 + wv * 16 + quad * 4 + r;
            biasC[g][r] = (b_ih[m] + b_hh[m]) * scale;
        }
    }

    // zero h buf 0 (h0 = 0); buf 1 fully written at t=0 before first read
    if (tid < 256) ((unsigned*)h_frag)[tid] = 0;

    // ---- packed-lane identity: element (col, nb) ----
    const int e    = c16 >> 2;
    const int nb   = c16 & 3;
    const int col  = wv * 16 + quad * 4 + e;
    const int waddr = (col >> 5) * 128 + ((col >> 3) & 3) * 32 + nb * 8 + (col & 7);
    // h read: valid lanes c16<4 read 16B at v*16 (v = quad*4+c16); others addr 0
    const int hoff = (c16 < 4) ? ((quad * 4 + c16) * 16) : 0;   // bytes within frag
    // x read: valid lanes quad<2 && c16<4
    const bool xv = (quad < 2) && (c16 < 4);
    const int xoff  = xv ? (quad * 64 + c16 * 16) : 0;          // bytes
    const int xmask = xv ? ~0 : 0;

    float c_st = 0.0f, h_ep = 0.0f;

    // ---- prologue: stage chunk 0 -> xlds[0]; chunk 1 -> xreg ----
    f32x4 xreg;
    {
        const int flat4 = tid * 4;
        const int b_loc = flat4 >> 9;
        const int rem   = flat4 & 511;
        const float* xr = x + (size_t)(b0 + b_loc) * (T_LEN * IN_DIM);
        f32x4 v4 = *(const f32x4*)(xr + rem);
        const int slot = rem >> 4, feat = rem & 15;
        unsigned* dst = (unsigned*)&xlds[0][slot][feat >> 3][b_loc][feat & 7];
        dst[0] = pk_bf16(v4[0], v4[1]);
        dst[1] = pk_bf16(v4[2], v4[3]);
        xreg = *(const f32x4*)(xr + CHUNK * IN_DIM + rem);
    }
    __syncthreads();

    // accN = bias + x-MFMA, one step ahead
    f32x4 accN[4];
    {
        s16x8 zx0 = *(const s16x8*)((const char*)xlds + (xoff & xmask));
        #pragma unroll
        for (int g = 0; g < 4; ++g)
            accN[g] = __builtin_amdgcn_mfma_f32_16x16x32_bf16(wfrag[g][4], zx0, biasC[g], 0, 0, 0);
    }

    auto step_fn = [&](const int RB, const int WB, const int t) {
        const char* hb = (const char*)h_frag[RB];
        s16x8 zf[4];
        #pragma unroll
        for (int kf = 0; kf < 4; ++kf)
            zf[kf] = *(const s16x8*)(hb + hoff + kf * 256);
        // x frag for t+1 (independent of h(t)) — load early
        const int ts  = t + 1;
        const int off = (((ts >> 5) & 1) * 4096 + (ts & 31) * 128 + xoff) & xmask;
        s16x8 zxn = *(const s16x8*)((const char*)xlds + off);

        // ---- gates 0,1: two interleaved dependent chains ----
        f32x4 a0 = accN[0], a1 = accN[1];
        #pragma unroll
        for (int kf = 0; kf < 4; ++kf) {
            a0 = __builtin_amdgcn_mfma_f32_16x16x32_bf16(wfrag[0][kf], zf[kf], a0, 0, 0, 0);
            a1 = __builtin_amdgcn_mfma_f32_16x16x32_bf16(wfrag[1][kf], zf[kf], a1, 0, 0, 0);
        }
        // ---- accN refresh (4 independent MFMAs keep the pipe fed) ----
        #pragma unroll
        for (int g = 0; g < 4; ++g)
            accN[g] = __builtin_amdgcn_mfma_f32_16x16x32_bf16(wfrag[g][4], zxn, biasC[g], 0, 0, 0);
        // ---- gates 2,3 chains ----
        f32x4 a2 = accN[2], a3 = accN[3];
        // NOTE: accN[2]/accN[3] were just overwritten for t+1 — must use saved copies.
        // (use the pre-refresh values: see below — a2/a3 seeded before refresh)
        (void)a2; (void)a3;
        // correctness: seed a2/a3 from the t-step accN BEFORE the refresh above.
        // To keep the schedule, we saved them here:
        // -- this lambda is rewritten below; see step_impl --
        (void)0;
    };
    (void)step_fn;

    // real step: explicit ordering with a2/a3 seeded before accN refresh
    auto step_impl = [&](const int RB, const int WB, const int t) {
        const char* hb = (const char*)h_frag[RB];
        s16x8 zf[4];
        #pragma unroll
        for (int kf = 0; kf < 4; ++kf)
            zf[kf] = *(const s16x8*)(hb + hoff + kf * 256);
        const int ts  = t + 1;
        const int off = (((ts >> 5) & 1) * 4096 + (ts & 31) * 128 + xoff) & xmask;
        s16x8 zxn = *(const s16x8*)((const char*)xlds + off);

        f32x4 a0 = accN[0], a1 = accN[1], a2 = accN[2], a3 = accN[3];

        // gates 0,1 chains (interleaved)
        #pragma unroll
        for (int kf = 0; kf < 4; ++kf) {
            a0 = __builtin_amdgcn_mfma_f32_16x16x32_bf16(wfrag[0][kf], zf[kf], a0, 0, 0, 0);
            a1 = __builtin_amdgcn_mfma_f32_16x16x32_bf16(wfrag[1][kf], zf[kf], a1, 0, 0, 0);
        }
        // accN refresh for t+1 (independent; fills dependent-chain stalls)
        #pragma unroll
        for (int g = 0; g < 4; ++g)
            accN[g] = __builtin_amdgcn_mfma_f32_16x16x32_bf16(wfrag[g][4], zxn, biasC[g], 0, 0, 0);
        // gates 2,3 chains
        #pragma unroll
        for (int kf = 0; kf < 4; ++kf) {
            a2 = __builtin_amdgcn_mfma_f32_16x16x32_bf16(wfrag[2][kf], zf[kf], a2, 0, 0, 0);
            a3 = __builtin_amdgcn_mfma_f32_16x16x32_bf16(wfrag[3][kf], zf[kf], a3, 0, 0, 0);
        }

        // early elementwise: i,f (and then g) exp2s issue while g2/g3 MFMAs drain
        const float di = pack4(a0[0], a0[1], a0[2], a0[3]);
        const float ei = __builtin_amdgcn_exp2f(di);
        const float df = pack4(a1[0], a1[1], a1[2], a1[3]);
        const float ef = __builtin_amdgcn_exp2f(df);
        const float dg = pack4(a2[0], a2[1], a2[2], a2[3]);
        const float eg = __builtin_amdgcn_exp2f(dg);

        const float af = 1.0f + ef;
        const float t1 = (1.0f + ei) * (1.0f + eg);
        const float num = fmaf(c_st, t1, (1.0f - eg) * af);
        const float cn  = num * __builtin_amdgcn_rcpf(af * t1);
        c_st = cn;
        const float ec = __builtin_amdgcn_exp2f(fminf(cn * (2.0f * kNL2E), 40.f));

        const float dojj = pack4(a3[0], a3[1], a3[2], a3[3]);
        const float eo = __builtin_amdgcn_exp2f(dojj);
        const float hn = (1.0f - ec) * __builtin_amdgcn_rcpf((1.0f + eo) * (1.0f + ec));
        h_ep = hn;
        h_frag[WB][waddr] = (unsigned short)f2bf(hn);   // one ds_write_b16
        __syncthreads();
    };

    for (int t = 0; t < T_LEN; t += 2) {
        step_impl(0, 1, t);

        // ---- spread x maintenance ----
        const int iter  = (t >> 1) & 15;
        const int cbase = t & ~(CHUNK - 1);
        if (iter < 2) {
            if (cbase + CHUNK < T_LEN) {
                const int flat4 = tid * 4;
                const int b_loc = flat4 >> 9;
                const int rem   = flat4 & 511;
                const int slot = rem >> 4, feat = rem & 15;
                const int nb1 = ((cbase >> 5) + 1) & 1;
                unsigned* dst = (unsigned*)&xlds[nb1][slot][feat >> 3][b_loc][(feat & 7) + 2 * iter];
                dst[0] = pk_bf16(xreg[2 * iter], xreg[2 * iter + 1]);
            }
        } else if (iter == 8) {
            const int tnext = cbase + 2 * CHUNK;
            if (tnext < T_LEN) {
                const int flat4 = tid * 4;
                const int b_loc = flat4 >> 9;
                const int rem   = flat4 & 511;
                xreg = *(const f32x4*)(x + (size_t)(b0 + b_loc) * (T_LEN * IN_DIM)
                                         + (size_t)tnext * IN_DIM + rem);
            }
        }

        step_impl(1, 0, t + 1);
    }

    // ---- epilogue: out[b] = sum_cols h * fc_w + fc_b ----
    float v = h_ep * fc_w[col];
    v += __shfl_xor(v, 4);
    v += __shfl_xor(v, 8);
    v += __shfl_xor(v, 16);
    v += __shfl_xor(v, 32);
    if (tid < NROWS) red[tid] = 0.0f;
    __syncthreads();
    if (lane < NROWS) atomicAdd(&red[nb], v);
    __syncthreads();
    if (tid < NROWS) out[b0 + tid] = red[tid] + fc_b[0];
}

extern "C" void kernel_launch(void* const* d_in, const int* in_sizes, int n_in,
                              void* d_out, int out_size, void* d_ws, size_t ws_size,
                              hipStream_t stream) {
    const float* x    = (const float*)d_in[0];
    const float* W_ih = (const float*)d_in[1];
    const float* W_hh = (const float*)d_in[2];
    const float* b_ih = (const float*)d_in[3];
    const float* b_hh = (const float*)d_in[4];
    const float* fc_w = (const float*)d_in[5];
    const float* fc_b = (const float*)d_in[6];
    float* out = (float*)d_out;

    slstm_persistent<<<256, 512, 0, stream>>>(x, W_ih, W_hh, b_ih, b_hh, fc_w, fc_b, out);
}